// Round 3
// baseline (160.560 us; speedup 1.0000x reference)
//
#include <hip/hip_runtime.h>

#define GD 128
#define GD3 (GD*GD*GD)
#define KP 27

typedef __attribute__((ext_vector_type(8))) __bf16 bf16x8;
typedef __attribute__((ext_vector_type(4))) float f32x4;
typedef __attribute__((ext_vector_type(4))) unsigned int u32x4;

__device__ __forceinline__ unsigned short f2bf(float x) {
  unsigned int u = __builtin_bit_cast(unsigned int, x);
  unsigned int r = (u + 0x7FFFu + ((u >> 16) & 1u)) >> 16;  // RNE
  return (unsigned short)r;
}

__global__ void k_init_grid(int* __restrict__ g) {
  int i = (blockIdx.x * 256 + threadIdx.x) * 4;
  if (i < GD3) *(u32x4*)(g + i) = (u32x4){0xFFFFFFFFu,0xFFFFFFFFu,0xFFFFFFFFu,0xFFFFFFFFu};
}

__global__ void k_scatter(const int* __restrict__ coords, int* __restrict__ g, int n) {
  int i = blockIdx.x * 256 + threadIdx.x;
  if (i >= n) return;
  int x = coords[3*i], y = coords[3*i+1], z = coords[3*i+2];
  g[(x << 14) | (y << 7) | z] = i;
}

// Pack w2 (27,16,32) and w3 (27,32,64) into MFMA B-fragment order, bf16.
// wpk[k][chunk][lane][j] = W[k][ci][co], ci=(lane>>4)*8+j, co=chunk*16+(lane&15).
// w2 zero-padded in ci to K=32. Two leftover threads zero row n of x1bf / x2bf.
__global__ void k_wpack(const float* __restrict__ w2, const float* __restrict__ w3,
                        unsigned short* __restrict__ w2pk, unsigned short* __restrict__ w3pk,
                        unsigned short* __restrict__ x1bf, unsigned short* __restrict__ x2bf,
                        int n) {
  int gid = blockIdx.x * 256 + threadIdx.x;
  const int N2 = KP * 2 * 64;
  const int N3 = KP * 4 * 64;
  if (gid < N2) {
    int k = gid >> 7, rem = gid & 127, c = rem >> 6, l = rem & 63;
    int gq = l >> 4, col = l & 15;
    #pragma unroll
    for (int j = 0; j < 8; j++) {
      int ci = gq * 8 + j, co = c * 16 + col;
      float v = (ci < 16) ? w2[(k * 16 + ci) * 32 + co] : 0.f;
      w2pk[gid * 8 + j] = f2bf(v);
    }
  } else if (gid < N2 + N3) {
    int g2 = gid - N2;
    int k = g2 >> 8, rem = g2 & 255, c = rem >> 6, l = rem & 63;
    int gq = l >> 4, col = l & 15;
    #pragma unroll
    for (int j = 0; j < 8; j++) {
      int ci = gq * 8 + j, co = c * 16 + col;
      float v = w3[(k * 32 + ci) * 64 + co];
      w3pk[g2 * 8 + j] = f2bf(v);
    }
  } else if (gid == N2 + N3) {
    u32x4 z = {0u,0u,0u,0u};
    u32x4* d = (u32x4*)(x1bf + (size_t)n * 32);
    d[0] = z; d[1] = z; d[2] = z; d[3] = z;
  } else if (gid == N2 + N3 + 1) {
    u32x4 z = {0u,0u,0u,0u};
    u32x4* d = (u32x4*)(x2bf + (size_t)n * 32);
    d[0] = z; d[1] = z; d[2] = z; d[3] = z;
  }
}

// Rulebook build (k-major, inactive -> n = zero row) fused with conv1 (1->16 ch, VALU).
__global__ void k_nbr_conv1(const int* __restrict__ coords, const float* __restrict__ feats,
                            const float* __restrict__ w1, const int* __restrict__ grid,
                            int* __restrict__ nbr, unsigned short* __restrict__ x1bf,
                            int n, int npad) {
  int i = blockIdx.x * 256 + threadIdx.x;
  if (i >= npad) return;
  if (i >= n) {
    #pragma unroll
    for (int k = 0; k < KP; k++) nbr[k*npad + i] = n;
    return;
  }
  int x = coords[3*i], y = coords[3*i+1], z = coords[3*i+2];
  float acc[16];
  #pragma unroll
  for (int c = 0; c < 16; c++) acc[c] = 0.f;
  #pragma unroll
  for (int k = 0; k < 27; k++) {
    const int dx = k/9 - 1, dy = (k/3)%3 - 1, dz = k%3 - 1;
    int nx = x+dx, ny = y+dy, nz = z+dz;
    int idx = -1;
    if (((unsigned)nx < 128u) && ((unsigned)ny < 128u) && ((unsigned)nz < 128u))
      idx = grid[(nx << 14) | (ny << 7) | nz];
    nbr[k*npad + i] = (idx >= 0) ? idx : n;
    float f = 0.f;
    if (idx >= 0) f = feats[idx];
    #pragma unroll
    for (int c = 0; c < 16; c++) acc[c] = fmaf(f, w1[k*16+c], acc[c]);
  }
  u32x4 d0, d1, dz4 = {0u,0u,0u,0u};
  d0.x = (unsigned)f2bf(acc[0])  | ((unsigned)f2bf(acc[1])  << 16);
  d0.y = (unsigned)f2bf(acc[2])  | ((unsigned)f2bf(acc[3])  << 16);
  d0.z = (unsigned)f2bf(acc[4])  | ((unsigned)f2bf(acc[5])  << 16);
  d0.w = (unsigned)f2bf(acc[6])  | ((unsigned)f2bf(acc[7])  << 16);
  d1.x = (unsigned)f2bf(acc[8])  | ((unsigned)f2bf(acc[9])  << 16);
  d1.y = (unsigned)f2bf(acc[10]) | ((unsigned)f2bf(acc[11]) << 16);
  d1.z = (unsigned)f2bf(acc[12]) | ((unsigned)f2bf(acc[13]) << 16);
  d1.w = (unsigned)f2bf(acc[14]) | ((unsigned)f2bf(acc[15]) << 16);
  u32x4* dst = (u32x4*)(x1bf + (size_t)i * 32);
  dst[0] = d0; dst[1] = d1; dst[2] = dz4; dst[3] = dz4;
}

// Gather-MFMA conv layer. Fully-unrolled k loop (compiler software-pipelines the
// unconditional loads), T=4 M-tiles (64 rows) per wave. Inactive gathers hit row n (zeros).
template<int CHUNKS>
__launch_bounds__(256, 2)
__global__ void k_conv(const int* __restrict__ nbr, const unsigned short* __restrict__ xin,
                       const unsigned short* __restrict__ wpk, unsigned short* __restrict__ xout,
                       const float* __restrict__ wm, const float* __restrict__ bm,
                       float* __restrict__ outf, int n, int npad) {
  const int lane = threadIdx.x & 63;
  const int wid = blockIdx.x * 4 + (threadIdx.x >> 6);
  const int base = wid * 64;
  if (base >= npad) return;
  const int col = lane & 15, grp = lane >> 4;
  const unsigned short* xin_g = xin + grp * 8;

  f32x4 acc[4][CHUNKS];
  #pragma unroll
  for (int t = 0; t < 4; t++)
    #pragma unroll
    for (int c = 0; c < CHUNKS; c++) acc[t][c] = (f32x4){0.f,0.f,0.f,0.f};

  #pragma unroll
  for (int k = 0; k < 27; ++k) {
    int idx[4];
    #pragma unroll
    for (int t = 0; t < 4; t++) idx[t] = nbr[(size_t)k * npad + base + t * 16 + col];
    bf16x8 a[4];
    #pragma unroll
    for (int t = 0; t < 4; t++) a[t] = *(const bf16x8*)(xin_g + (size_t)idx[t] * 32);
    bf16x8 b[CHUNKS];
    #pragma unroll
    for (int c = 0; c < CHUNKS; c++)
      b[c] = *(const bf16x8*)(wpk + ((size_t)((k * CHUNKS + c) * 64 + lane)) * 8);
    #pragma unroll
    for (int c = 0; c < CHUNKS; c++)
      #pragma unroll
      for (int t = 0; t < 4; t++)
        acc[t][c] = __builtin_amdgcn_mfma_f32_16x16x32_bf16(a[t], b[c], acc[t][c], 0, 0, 0);
  }

  if constexpr (CHUNKS == 2) {
    #pragma unroll
    for (int t = 0; t < 4; t++)
      #pragma unroll
      for (int c = 0; c < CHUNKS; c++)
        #pragma unroll
        for (int r = 0; r < 4; r++) {
          int m = base + t*16 + grp*4 + r;
          if (m < n) xout[(size_t)m * 32 + c*16 + col] = f2bf(acc[t][c][r]);
        }
  } else {
    float wmv[CHUNKS][3];
    #pragma unroll
    for (int c = 0; c < CHUNKS; c++)
      #pragma unroll
      for (int j = 0; j < 3; j++) wmv[c][j] = wm[(c*16 + col)*3 + j];
    float bb0 = bm[0], bb1 = bm[1], bb2 = bm[2];
    #pragma unroll
    for (int t = 0; t < 4; t++)
      #pragma unroll
      for (int r = 0; r < 4; r++) {
        float p0 = 0.f, p1 = 0.f, p2 = 0.f;
        #pragma unroll
        for (int c = 0; c < CHUNKS; c++) {
          float v = acc[t][c][r];
          p0 = fmaf(v, wmv[c][0], p0);
          p1 = fmaf(v, wmv[c][1], p1);
          p2 = fmaf(v, wmv[c][2], p2);
        }
        #pragma unroll
        for (int msk = 1; msk <= 8; msk <<= 1) {
          p0 += __shfl_xor(p0, msk);
          p1 += __shfl_xor(p1, msk);
          p2 += __shfl_xor(p2, msk);
        }
        if (col == 0) {
          int m = base + t*16 + grp*4 + r;
          if (m < n) {
            outf[m*3+0] = p0 + bb0;
            outf[m*3+1] = p1 + bb1;
            outf[m*3+2] = p2 + bb2;
          }
        }
      }
  }
}

extern "C" void kernel_launch(void* const* d_in, const int* in_sizes, int n_in,
                              void* d_out, int out_size, void* d_ws, size_t ws_size,
                              hipStream_t stream) {
  (void)n_in; (void)out_size; (void)ws_size;
  const int*   coords = (const int*)d_in[0];
  const float* feats  = (const float*)d_in[1];
  const float* w1     = (const float*)d_in[2];
  const float* w2     = (const float*)d_in[3];
  const float* w3     = (const float*)d_in[4];
  const float* wm     = (const float*)d_in[5];
  const float* bm     = (const float*)d_in[6];
  float* outf = (float*)d_out;
  const int n = in_sizes[0] / 3;
  const int npad = (n + 63) & ~63;

  char* ws = (char*)d_ws;
  size_t off = 0;
  int* grid = (int*)(ws + off); off += (size_t)GD3 * 4;
  int* nbr  = (int*)(ws + off); off += (size_t)KP * npad * 4;
  off = (off + 255) & ~(size_t)255;
  unsigned short* x1bf = (unsigned short*)(ws + off); off += ((size_t)n + 1) * 32 * 2;
  off = (off + 255) & ~(size_t)255;
  unsigned short* x2bf = (unsigned short*)(ws + off); off += ((size_t)n + 1) * 32 * 2;
  off = (off + 255) & ~(size_t)255;
  unsigned short* w2pk = (unsigned short*)(ws + off); off += (size_t)KP * 2 * 64 * 8 * 2;
  off = (off + 255) & ~(size_t)255;
  unsigned short* w3pk = (unsigned short*)(ws + off); off += (size_t)KP * 4 * 64 * 8 * 2;

  hipLaunchKernelGGL(k_init_grid, dim3(GD3 / 1024), dim3(256), 0, stream, grid);
  hipLaunchKernelGGL(k_scatter, dim3((n + 255) / 256), dim3(256), 0, stream, coords, grid, n);
  {
    const int items = KP * 2 * 64 + KP * 4 * 64 + 2;
    hipLaunchKernelGGL(k_wpack, dim3((items + 255) / 256), dim3(256), 0, stream,
                       w2, w3, w2pk, w3pk, x1bf, x2bf, n);
  }
  hipLaunchKernelGGL(k_nbr_conv1, dim3((npad + 255) / 256), dim3(256), 0, stream,
                     coords, feats, w1, grid, nbr, x1bf, n, npad);
  const int waves = npad / 64;
  const int cblocks = (waves + 3) / 4;
  hipLaunchKernelGGL((k_conv<2>), dim3(cblocks), dim3(256), 0, stream,
                     nbr, x1bf, w2pk, x2bf, nullptr, nullptr, nullptr, n, npad);
  hipLaunchKernelGGL((k_conv<4>), dim3(cblocks), dim3(256), 0, stream,
                     nbr, x2bf, w3pk, nullptr, wm, bm, outf, n, npad);
}

// Round 4
// 138.061 us; speedup vs baseline: 1.1630x; 1.1630x over previous
//
#include <hip/hip_runtime.h>

#define GD 128
#define GD3 (GD*GD*GD)
#define KP 27
#define CPB 2048              // cells per block in count/compact
#define NSCAN (GD3 / CPB)     // 1024 scan blocks

typedef __attribute__((ext_vector_type(8))) __bf16 bf16x8;
typedef __attribute__((ext_vector_type(4))) float f32x4;
typedef __attribute__((ext_vector_type(4))) unsigned int u32x4;

__device__ __forceinline__ unsigned short f2bf(float x) {
  unsigned int u = __builtin_bit_cast(unsigned int, x);
  unsigned int r = (u + 0x7FFFu + ((u >> 16) & 1u)) >> 16;  // RNE
  return (unsigned short)r;
}

// Bijective XCD-chunked block swizzle (m204): contiguous work chunk per XCD.
__device__ __forceinline__ int xcd_swz(int bid, int nwg) {
  int q = nwg >> 3, r = nwg & 7;
  int x = bid & 7, inner = bid >> 3;
  int base = (x < r) ? x * (q + 1) : r * (q + 1) + (x - r) * q;
  return base + inner;
}

__global__ void k_init_grid(int* __restrict__ g) {
  int i = (blockIdx.x * 256 + threadIdx.x) * 4;
  if (i < GD3) *(u32x4*)(g + i) = (u32x4){0xFFFFFFFFu,0xFFFFFFFFu,0xFFFFFFFFu,0xFFFFFFFFu};
}

__global__ void k_scatter(const int* __restrict__ coords, int* __restrict__ g, int n) {
  int i = blockIdx.x * 256 + threadIdx.x;
  if (i >= n) return;
  int x = coords[3*i], y = coords[3*i+1], z = coords[3*i+2];
  g[(x << 14) | (y << 7) | z] = i;
}

// Per-block occupied-cell counts (2048 cells/block).
__global__ void k_count(const int* __restrict__ g, int* __restrict__ bcnt) {
  __shared__ int wtot[4];
  int t = threadIdx.x, lane = t & 63, w = t >> 6;
  const int* c = g + blockIdx.x * CPB + t * 8;
  int cnt = 0;
  #pragma unroll
  for (int j = 0; j < 8; j++) cnt += (c[j] >= 0) ? 1 : 0;
  #pragma unroll
  for (int d = 1; d < 64; d <<= 1) cnt += __shfl_xor(cnt, d);
  if (lane == 0) wtot[w] = cnt;
  __syncthreads();
  if (t == 0) bcnt[blockIdx.x] = wtot[0] + wtot[1] + wtot[2] + wtot[3];
}

// Exclusive scan of the 1024 block counts (single block, 1024 threads).
__global__ void k_scan(const int* __restrict__ bcnt, int* __restrict__ boff) {
  __shared__ int s[NSCAN];
  int t = threadIdx.x;
  int v = bcnt[t];
  s[t] = v;
  __syncthreads();
  #pragma unroll
  for (int d = 1; d < NSCAN; d <<= 1) {
    int y = (t >= d) ? s[t - d] : 0;
    __syncthreads();
    s[t] += y;
    __syncthreads();
  }
  boff[t] = s[t] - v;
}

// Compact: rank grid (cell -> sorted idx, -1 if empty), sorted_of, sorted lin, sorted feats.
__global__ void k_compact(const int* __restrict__ g, const float* __restrict__ feats,
                          const int* __restrict__ boff, int* __restrict__ g2,
                          int* __restrict__ sof, int* __restrict__ slin,
                          float* __restrict__ featss) {
  __shared__ int wtot[4];
  int t = threadIdx.x, lane = t & 63, w = t >> 6;
  int cbase = blockIdx.x * CPB + t * 8;
  int v[8]; int cnt = 0;
  #pragma unroll
  for (int j = 0; j < 8; j++) { v[j] = g[cbase + j]; cnt += (v[j] >= 0) ? 1 : 0; }
  int x = cnt;
  #pragma unroll
  for (int d = 1; d < 64; d <<= 1) { int y = __shfl_up(x, d); if (lane >= d) x += y; }
  if (lane == 63) wtot[w] = x;
  __syncthreads();
  int wbase = 0;
  for (int ww = 0; ww < w; ww++) wbase += wtot[ww];
  int pos = boff[blockIdx.x] + wbase + (x - cnt);
  #pragma unroll
  for (int j = 0; j < 8; j++) {
    int o = v[j];
    if (o >= 0) {
      g2[cbase + j] = pos;
      sof[pos] = o;
      slin[pos] = cbase + j;
      featss[pos] = feats[o];
      pos++;
    } else {
      g2[cbase + j] = -1;
    }
  }
}

// Pack w2 (27,16,32) and w3 (27,32,64) into MFMA B-fragment order, bf16.
// wpk[k][chunk][lane][j] = W[k][ci][co], ci=(lane>>4)*8+j, co=chunk*16+(lane&15).
// Two leftover threads zero row n of x1bf / x2bf.
__global__ void k_wpack(const float* __restrict__ w2, const float* __restrict__ w3,
                        unsigned short* __restrict__ w2pk, unsigned short* __restrict__ w3pk,
                        unsigned short* __restrict__ x1bf, unsigned short* __restrict__ x2bf,
                        int n) {
  int gid = blockIdx.x * 256 + threadIdx.x;
  const int N2 = KP * 2 * 64;
  const int N3 = KP * 4 * 64;
  if (gid < N2) {
    int k = gid >> 7, rem = gid & 127, c = rem >> 6, l = rem & 63;
    int gq = l >> 4, col = l & 15;
    #pragma unroll
    for (int j = 0; j < 8; j++) {
      int ci = gq * 8 + j, co = c * 16 + col;
      float v = (ci < 16) ? w2[(k * 16 + ci) * 32 + co] : 0.f;
      w2pk[gid * 8 + j] = f2bf(v);
    }
  } else if (gid < N2 + N3) {
    int g2 = gid - N2;
    int k = g2 >> 8, rem = g2 & 255, c = rem >> 6, l = rem & 63;
    int gq = l >> 4, col = l & 15;
    #pragma unroll
    for (int j = 0; j < 8; j++) {
      int ci = gq * 8 + j, co = c * 16 + col;
      float v = w3[(k * 32 + ci) * 64 + co];
      w3pk[g2 * 8 + j] = f2bf(v);
    }
  } else if (gid == N2 + N3) {
    u32x4 z = {0u,0u,0u,0u};
    u32x4* d = (u32x4*)(x1bf + (size_t)n * 32);
    d[0] = z; d[1] = z; d[2] = z; d[3] = z;
  } else if (gid == N2 + N3 + 1) {
    u32x4 z = {0u,0u,0u,0u};
    u32x4* d = (u32x4*)(x2bf + (size_t)n * 32);
    d[0] = z; d[1] = z; d[2] = z; d[3] = z;
  }
}

// Rulebook build in SORTED space (inactive -> n = zero row) fused with conv1.
__global__ void k_nbr_conv1(const int* __restrict__ slin, const float* __restrict__ featss,
                            const float* __restrict__ w1, const int* __restrict__ g2,
                            int* __restrict__ nbr, unsigned short* __restrict__ x1bf,
                            int n, int npad) {
  int bid = xcd_swz(blockIdx.x, gridDim.x);
  int i = bid * 256 + threadIdx.x;
  if (i >= npad) return;
  if (i >= n) {
    #pragma unroll
    for (int k = 0; k < KP; k++) nbr[k*npad + i] = n;
    return;
  }
  int lin = slin[i];
  int x = lin >> 14, y = (lin >> 7) & 127, z = lin & 127;
  float acc[16];
  #pragma unroll
  for (int c = 0; c < 16; c++) acc[c] = 0.f;
  #pragma unroll
  for (int k = 0; k < 27; k++) {
    const int dx = k/9 - 1, dy = (k/3)%3 - 1, dz = k%3 - 1;
    int nx = x+dx, ny = y+dy, nz = z+dz;
    int idx = -1;
    if (((unsigned)nx < 128u) && ((unsigned)ny < 128u) && ((unsigned)nz < 128u))
      idx = g2[(nx << 14) | (ny << 7) | nz];
    nbr[k*npad + i] = (idx >= 0) ? idx : n;
    float f = 0.f;
    if (idx >= 0) f = featss[idx];
    #pragma unroll
    for (int c = 0; c < 16; c++) acc[c] = fmaf(f, w1[k*16+c], acc[c]);
  }
  u32x4 d0, d1, dz4 = {0u,0u,0u,0u};
  d0.x = (unsigned)f2bf(acc[0])  | ((unsigned)f2bf(acc[1])  << 16);
  d0.y = (unsigned)f2bf(acc[2])  | ((unsigned)f2bf(acc[3])  << 16);
  d0.z = (unsigned)f2bf(acc[4])  | ((unsigned)f2bf(acc[5])  << 16);
  d0.w = (unsigned)f2bf(acc[6])  | ((unsigned)f2bf(acc[7])  << 16);
  d1.x = (unsigned)f2bf(acc[8])  | ((unsigned)f2bf(acc[9])  << 16);
  d1.y = (unsigned)f2bf(acc[10]) | ((unsigned)f2bf(acc[11]) << 16);
  d1.z = (unsigned)f2bf(acc[12]) | ((unsigned)f2bf(acc[13]) << 16);
  d1.w = (unsigned)f2bf(acc[14]) | ((unsigned)f2bf(acc[15]) << 16);
  u32x4* dst = (u32x4*)(x1bf + (size_t)i * 32);
  dst[0] = d0; dst[1] = d1; dst[2] = dz4; dst[3] = dz4;
}

// Gather-MFMA conv layer in sorted space. Full k-unroll, T=2 M-tiles (32 rows)/wave.
// CHUNKS==4 fuses the 64->3 head and scatters to original row order via sof.
template<int CHUNKS>
__launch_bounds__(256)
__global__ void k_conv(const int* __restrict__ nbr, const unsigned short* __restrict__ xin,
                       const unsigned short* __restrict__ wpk, unsigned short* __restrict__ xout,
                       const float* __restrict__ wm, const float* __restrict__ bm,
                       float* __restrict__ outf, const int* __restrict__ sof,
                       int n, int npad) {
  const int lane = threadIdx.x & 63;
  const int bid = xcd_swz(blockIdx.x, gridDim.x);
  const int wid = bid * 4 + (threadIdx.x >> 6);
  const int base = wid * 32;
  if (base >= npad) return;
  const int col = lane & 15, grp = lane >> 4;
  const unsigned short* xin_g = xin + grp * 8;

  f32x4 acc[2][CHUNKS];
  #pragma unroll
  for (int t = 0; t < 2; t++)
    #pragma unroll
    for (int c = 0; c < CHUNKS; c++) acc[t][c] = (f32x4){0.f,0.f,0.f,0.f};

  #pragma unroll
  for (int k = 0; k < 27; ++k) {
    int idx[2];
    #pragma unroll
    for (int t = 0; t < 2; t++) idx[t] = nbr[(size_t)k * npad + base + t * 16 + col];
    bf16x8 a[2];
    #pragma unroll
    for (int t = 0; t < 2; t++) a[t] = *(const bf16x8*)(xin_g + (size_t)idx[t] * 32);
    bf16x8 b[CHUNKS];
    #pragma unroll
    for (int c = 0; c < CHUNKS; c++)
      b[c] = *(const bf16x8*)(wpk + ((size_t)((k * CHUNKS + c) * 64 + lane)) * 8);
    #pragma unroll
    for (int c = 0; c < CHUNKS; c++)
      #pragma unroll
      for (int t = 0; t < 2; t++)
        acc[t][c] = __builtin_amdgcn_mfma_f32_16x16x32_bf16(a[t], b[c], acc[t][c], 0, 0, 0);
  }

  if constexpr (CHUNKS == 2) {
    #pragma unroll
    for (int t = 0; t < 2; t++)
      #pragma unroll
      for (int c = 0; c < CHUNKS; c++)
        #pragma unroll
        for (int r = 0; r < 4; r++) {
          int m = base + t*16 + grp*4 + r;
          if (m < n) xout[(size_t)m * 32 + c*16 + col] = f2bf(acc[t][c][r]);
        }
  } else {
    float wmv[CHUNKS][3];
    #pragma unroll
    for (int c = 0; c < CHUNKS; c++)
      #pragma unroll
      for (int j = 0; j < 3; j++) wmv[c][j] = wm[(c*16 + col)*3 + j];
    float bb0 = bm[0], bb1 = bm[1], bb2 = bm[2];
    #pragma unroll
    for (int t = 0; t < 2; t++)
      #pragma unroll
      for (int r = 0; r < 4; r++) {
        float p0 = 0.f, p1 = 0.f, p2 = 0.f;
        #pragma unroll
        for (int c = 0; c < CHUNKS; c++) {
          float v = acc[t][c][r];
          p0 = fmaf(v, wmv[c][0], p0);
          p1 = fmaf(v, wmv[c][1], p1);
          p2 = fmaf(v, wmv[c][2], p2);
        }
        #pragma unroll
        for (int msk = 1; msk <= 8; msk <<= 1) {
          p0 += __shfl_xor(p0, msk);
          p1 += __shfl_xor(p1, msk);
          p2 += __shfl_xor(p2, msk);
        }
        if (col == 0) {
          int m = base + t*16 + grp*4 + r;
          if (m < n) {
            int o = sof[m];
            outf[o*3+0] = p0 + bb0;
            outf[o*3+1] = p1 + bb1;
            outf[o*3+2] = p2 + bb2;
          }
        }
      }
  }
}

extern "C" void kernel_launch(void* const* d_in, const int* in_sizes, int n_in,
                              void* d_out, int out_size, void* d_ws, size_t ws_size,
                              hipStream_t stream) {
  (void)n_in; (void)out_size; (void)ws_size;
  const int*   coords = (const int*)d_in[0];
  const float* feats  = (const float*)d_in[1];
  const float* w1     = (const float*)d_in[2];
  const float* w2     = (const float*)d_in[3];
  const float* w3     = (const float*)d_in[4];
  const float* wm     = (const float*)d_in[5];
  const float* bm     = (const float*)d_in[6];
  float* outf = (float*)d_out;
  const int n = in_sizes[0] / 3;
  const int npad = (n + 31) & ~31;

  char* ws = (char*)d_ws;
  size_t off = 0;
  int* grid = (int*)(ws + off); off += (size_t)GD3 * 4;
  int* g2   = (int*)(ws + off); off += (size_t)GD3 * 4;
  int* nbr  = (int*)(ws + off); off += (size_t)KP * npad * 4;
  off = (off + 255) & ~(size_t)255;
  int* bcnt = (int*)(ws + off); off += (size_t)NSCAN * 4;
  int* boff = (int*)(ws + off); off += (size_t)NSCAN * 4;
  off = (off + 255) & ~(size_t)255;
  int* sof  = (int*)(ws + off); off += (size_t)npad * 4;
  int* slin = (int*)(ws + off); off += (size_t)npad * 4;
  float* featss = (float*)(ws + off); off += (size_t)npad * 4;
  off = (off + 255) & ~(size_t)255;
  unsigned short* x1bf = (unsigned short*)(ws + off); off += ((size_t)n + 1) * 32 * 2;
  off = (off + 255) & ~(size_t)255;
  unsigned short* x2bf = (unsigned short*)(ws + off); off += ((size_t)n + 1) * 32 * 2;
  off = (off + 255) & ~(size_t)255;
  unsigned short* w2pk = (unsigned short*)(ws + off); off += (size_t)KP * 2 * 64 * 8 * 2;
  off = (off + 255) & ~(size_t)255;
  unsigned short* w3pk = (unsigned short*)(ws + off); off += (size_t)KP * 4 * 64 * 8 * 2;

  hipLaunchKernelGGL(k_init_grid, dim3(GD3 / 1024), dim3(256), 0, stream, grid);
  hipLaunchKernelGGL(k_scatter, dim3((n + 255) / 256), dim3(256), 0, stream, coords, grid, n);
  hipLaunchKernelGGL(k_count, dim3(NSCAN), dim3(256), 0, stream, grid, bcnt);
  hipLaunchKernelGGL(k_scan, dim3(1), dim3(NSCAN), 0, stream, bcnt, boff);
  hipLaunchKernelGGL(k_compact, dim3(NSCAN), dim3(256), 0, stream,
                     grid, feats, boff, g2, sof, slin, featss);
  {
    const int items = KP * 2 * 64 + KP * 4 * 64 + 2;
    hipLaunchKernelGGL(k_wpack, dim3((items + 255) / 256), dim3(256), 0, stream,
                       w2, w3, w2pk, w3pk, x1bf, x2bf, n);
  }
  hipLaunchKernelGGL(k_nbr_conv1, dim3((npad + 255) / 256), dim3(256), 0, stream,
                     slin, featss, w1, g2, nbr, x1bf, n, npad);
  const int waves = npad / 32;
  const int cblocks = (waves + 3) / 4;
  hipLaunchKernelGGL((k_conv<2>), dim3(cblocks), dim3(256), 0, stream,
                     nbr, x1bf, w2pk, x2bf, nullptr, nullptr, nullptr, nullptr, n, npad);
  hipLaunchKernelGGL((k_conv<4>), dim3(cblocks), dim3(256), 0, stream,
                     nbr, x2bf, w3pk, nullptr, wm, bm, outf, sof, n, npad);
}